// Round 7
// baseline (156.875 us; speedup 1.0000x reference)
//
#include <hip/hip_runtime.h>
#include <hip/hip_bf16.h>
#include <math.h>

#define NB 16
#define NT 2048
#define ND 512
#define NH 64

typedef __attribute__((ext_vector_type(8))) short short8;
typedef __attribute__((ext_vector_type(4))) float float4v;

// ---------------------------------------------------------------------------
// mask dtype robustness: byte layout -> first int32 reads 0x01010101 (lengths
// >= T/2 so mask[0..3] all true); int32 layout -> 1; f32 layout -> 0x3F800000.
// ---------------------------------------------------------------------------
__device__ __forceinline__ bool mask_is_bytes(const int* m) {
    return m[0] == 0x01010101;
}
__device__ __forceinline__ bool mask_at(const int* m, bool bytes, int i) {
    if (bytes) return ((const unsigned char*)m)[i] != 0;
    return m[i] != 0;
}

__device__ __forceinline__ float dot4(float4 a, float4 p) {
    float d = a.x * p.x;
    d = __builtin_fmaf(a.y, p.y, d);
    d = __builtin_fmaf(a.z, p.z, d);
    d = __builtin_fmaf(a.w, p.w, d);
    return d;
}

// round-to-nearest-even f32 -> bf16 (values are finite here)
__device__ __forceinline__ unsigned short f2bf(float x) {
    unsigned int u = __float_as_uint(x);
    u += 0x7fffu + ((u >> 16) & 1u);
    return (unsigned short)(u >> 16);
}

// ---------------------------------------------------------------------------
// Kernel A: tokens -> four-vectors P (masked slots = (-1e30,0,0,0)), PLUS
// one-time W2 fp32[k][n] -> bf16 W2t[n][k] conversion.
// ---------------------------------------------------------------------------
__global__ void __launch_bounds__(256) compute_P_kernel(
        const float* __restrict__ tok,
        const int* __restrict__ mask,
        float4* __restrict__ P,
        unsigned short* __restrict__ W2t,
        const float* __restrict__ W2) {
    const bool mb = mask_is_bytes(mask);
    int i = blockIdx.x * 256 + threadIdx.x;

    float4 t = ((const float4*)tok)[i];
    float E = t.x, Pt = t.y, eta = t.z, phi = t.w;
    float px = Pt * cosf(phi);
    float py = Pt * sinf(phi);
    float pz = Pt * sinhf(fminf(fmaxf(eta, -20.f), 20.f));
    bool m = mask_at(mask, mb, i);
    P[i] = m ? make_float4(E, px, py, pz)
             : make_float4(-1e30f, 0.f, 0.f, 0.f);

    int n = i & 511, k = i >> 9;
    W2t[n * NH + k] = f2bf(W2[k * ND + n]);
}

// ---------------------------------------------------------------------------
// Kernel B (R6 + psum-atomic diet): 8 waves/block, 64 tokens/block, P-row in
// LDS, L-trimmed scans. CHANGE vs R6: per-wave psum slices (24 KB) replaced
// by one [12][64] buffer (3 KB) accumulated with LDS atomicAdd (ds_add_f32).
// LDS 74.2 KB -> ~51 KB => 3 blocks/CU (24 waves/CU, was 16).
// ---------------------------------------------------------------------------
__global__ void __launch_bounds__(512) topk_mass_kernel(
        const float4* __restrict__ P,
        const int* __restrict__ mask,
        float* __restrict__ massOut) {
    __shared__ float Plds[NT * 4];        // 32 KB
    __shared__ float vtop[8][8][64];      // 16 KB
    __shared__ float psum[12][64];        // 3 KB (atomic accum)
    __shared__ int wcnt[8];

    const int b    = blockIdx.y;
    const int t0   = blockIdx.x * 64;
    const int tid  = threadIdx.x;
    const int lane = tid & 63;
    const int w    = tid >> 6;
    const bool mb  = mask_is_bytes(mask);

    if (!mask_at(mask, mb, b * NT + t0)) {
        if (tid < 64) {
            float mz = sqrtf(1e-8f);
            int o = (b * NT + t0 + lane) * 3;
            massOut[o + 0] = mz;
            massOut[o + 1] = mz;
            massOut[o + 2] = mz;
        }
        return;
    }

    const float4* Pb = P + b * NT;
    int cnt = 0;
    for (int i = tid; i < NT; i += 512) {
        float4 v = Pb[i];
        *(float4*)&Plds[i * 4] = v;
        cnt += (int)__popcll(__ballot(v.x != -1e30f));
    }
    if (lane == 0) wcnt[w] = cnt;
    // zero the atomic psum buffer (768 floats / 512 threads)
    if (tid < 384) {
        ((float2*)psum)[tid] = make_float2(0.f, 0.f);
    }
    __syncthreads();                       // B1

    int L = 0;
#pragma unroll
    for (int j = 0; j < 8; ++j) L += wcnt[j];
    const int C    = (L + 7) >> 3;
    const int sBeg = w * C;
    const int sEnd = min(sBeg + C, L);

    const int t = t0 + lane;
    const bool maskt = mask_at(mask, mb, b * NT + t);
    float4 pt = *(const float4*)&Plds[(t0 + lane) * 4];
    float4 a  = make_float4(pt.x, -pt.y, -pt.z, -pt.w);

    const float NEGBIG = -3.402823466e38f;
    float v0 = NEGBIG, v1 = NEGBIG, v2 = NEGBIG, v3 = NEGBIG;
    float v4 = NEGBIG, v5 = NEGBIG, v6 = NEGBIG, v7 = NEGBIG;

#pragma unroll 4
    for (int s = sBeg; s < sEnd; ++s) {
        float4 ps = *(const float4*)&Plds[s * 4];
        float d = dot4(a, ps);
        float n0 = fmaxf(v0, d);
        float n1 = __builtin_amdgcn_fmed3f(d, v0, v1);
        float n2 = __builtin_amdgcn_fmed3f(d, v1, v2);
        float n3 = __builtin_amdgcn_fmed3f(d, v2, v3);
        float n4 = __builtin_amdgcn_fmed3f(d, v3, v4);
        float n5 = __builtin_amdgcn_fmed3f(d, v4, v5);
        float n6 = __builtin_amdgcn_fmed3f(d, v5, v6);
        float n7 = __builtin_amdgcn_fmed3f(d, v6, v7);
        v0 = n0; v1 = n1; v2 = n2; v3 = n3;
        v4 = n4; v5 = n5; v6 = n6; v7 = n7;
    }

    vtop[w][0][lane] = v0; vtop[w][1][lane] = v1;
    vtop[w][2][lane] = v2; vtop[w][3][lane] = v3;
    vtop[w][4][lane] = v4; vtop[w][5][lane] = v5;
    vtop[w][6][lane] = v6; vtop[w][7][lane] = v7;
    __syncthreads();                       // B2

    float m0 = NEGBIG, m1 = NEGBIG, m2_ = NEGBIG, m3 = NEGBIG;
    float m4 = NEGBIG, m5 = NEGBIG, m6 = NEGBIG, m7 = NEGBIG;
#pragma unroll
    for (int w2 = 0; w2 < 8; ++w2) {
#pragma unroll
        for (int j = 0; j < 8; ++j) {
            float d = vtop[w2][j][lane];
            float n0 = fmaxf(m0, d);
            float n1 = __builtin_amdgcn_fmed3f(d, m0, m1);
            float n2 = __builtin_amdgcn_fmed3f(d, m1, m2_);
            float n3 = __builtin_amdgcn_fmed3f(d, m2_, m3);
            float n4 = __builtin_amdgcn_fmed3f(d, m3, m4);
            float n5 = __builtin_amdgcn_fmed3f(d, m4, m5);
            float n6 = __builtin_amdgcn_fmed3f(d, m5, m6);
            float n7 = __builtin_amdgcn_fmed3f(d, m6, m7);
            m0 = n0; m1 = n1; m2_ = n2; m3 = n3;
            m4 = n4; m5 = n5; m6 = n6; m7 = n7;
        }
    }
    const float th2 = m1, th4 = m3, th8 = m7;

    float s2x = 0.f, s2y = 0.f, s2z = 0.f, s2w = 0.f;
    float s4x = 0.f, s4y = 0.f, s4z = 0.f, s4w = 0.f;
    float s8x = 0.f, s8y = 0.f, s8z = 0.f, s8w = 0.f;
#pragma unroll 4
    for (int s = sBeg; s < sEnd; ++s) {
        float4 ps = *(const float4*)&Plds[s * 4];
        float d = dot4(a, ps);
        if (d >= th8) {
            s8x += ps.x; s8y += ps.y; s8z += ps.z; s8w += ps.w;
            if (d >= th4) {
                s4x += ps.x; s4y += ps.y; s4z += ps.z; s4w += ps.w;
                if (d >= th2) {
                    s2x += ps.x; s2y += ps.y; s2z += ps.z; s2w += ps.w;
                }
            }
        }
    }
    // atomic accumulate (ds_add_f32); addresses lane-contiguous -> 2-way free
    atomicAdd(&psum[0][lane], s2x);  atomicAdd(&psum[1][lane], s2y);
    atomicAdd(&psum[2][lane], s2z);  atomicAdd(&psum[3][lane], s2w);
    atomicAdd(&psum[4][lane], s4x);  atomicAdd(&psum[5][lane], s4y);
    atomicAdd(&psum[6][lane], s4z);  atomicAdd(&psum[7][lane], s4w);
    atomicAdd(&psum[8][lane], s8x);  atomicAdd(&psum[9][lane], s8y);
    atomicAdd(&psum[10][lane], s8z); atomicAdd(&psum[11][lane], s8w);
    __syncthreads();                       // B3

    if (tid < 64) {
        auto massf = [&](float sx, float sy, float sz, float sw) -> float {
            float q = sx * sx;
            q = __builtin_fmaf(-sy, sy, q);
            q = __builtin_fmaf(-sz, sz, q);
            q = __builtin_fmaf(-sw, sw, q);
            q = fmaxf(q, 0.f);
            if (!maskt) q = 0.f;
            return sqrtf(q + 1e-8f);
        };
        int o = (b * NT + t) * 3;
        massOut[o + 0] = massf(psum[0][lane], psum[1][lane], psum[2][lane], psum[3][lane]);
        massOut[o + 1] = massf(psum[4][lane], psum[5][lane], psum[6][lane], psum[7][lane]);
        massOut[o + 2] = massf(psum[8][lane], psum[9][lane], psum[10][lane], psum[11][lane]);
    }
}

// ---------------------------------------------------------------------------
// Kernel C (unchanged R4): MFMA MLP. Block = 256 thr (4 waves), 32 tokens.
// Layouts: A[m=lane&15][k=quad*8+j]; B[n=lane&15][k=quad*8+j];
// D col=lane&15 (n), row=quad*4+reg (m).
// ---------------------------------------------------------------------------
__global__ void __launch_bounds__(256) mlp_kernel(
        const float* __restrict__ mass,
        const float* __restrict__ W1,
        const float* __restrict__ b1,
        const unsigned short* __restrict__ W2t,
        const float* __restrict__ b2,
        float* __restrict__ out) {
    __shared__ unsigned short hs[32][80];   // 5 KB, 160 B rows (16B-aligned)

    const int tid  = threadIdx.x;
    const int lane = tid & 63;
    const int wv   = tid >> 6;              // 0..3
    const int tokBase = blockIdx.x * 32;

    {
        const int tt = tid & 31;
        const int hr = tid >> 5;            // 0..7
        const int tokg = tokBase + tt;
        float m0 = mass[tokg * 3 + 0];
        float m1 = mass[tokg * 3 + 1];
        float m2 = mass[tokg * 3 + 2];
        unsigned short hv[8];
#pragma unroll
        for (int j = 0; j < 8; ++j) {
            int hh = hr * 8 + j;
            float pre = b1[hh];
            pre = __builtin_fmaf(m0, W1[hh], pre);
            pre = __builtin_fmaf(m1, W1[NH + hh], pre);
            pre = __builtin_fmaf(m2, W1[2 * NH + hh], pre);
            float g = 0.5f * pre * (1.0f + erff(pre * 0.70710678118654752f));
            hv[j] = f2bf(g);
        }
        *(short8*)&hs[tt][hr * 8] = *(const short8*)hv;
    }
    __syncthreads();

    const int col  = lane & 15;
    const int quad = lane >> 4;
    const int nBase = wv * 128;

    short8 afrag[2][2];
#pragma unroll
    for (int mt = 0; mt < 2; ++mt)
#pragma unroll
        for (int ks = 0; ks < 2; ++ks)
            afrag[mt][ks] = *(const short8*)&hs[mt * 16 + col][ks * 32 + quad * 8];

    float4v acc[2][8];
#pragma unroll
    for (int mt = 0; mt < 2; ++mt)
#pragma unroll
        for (int nt = 0; nt < 8; ++nt)
            acc[mt][nt] = (float4v)(0.f);

#pragma unroll
    for (int nt = 0; nt < 8; ++nt) {
        const unsigned short* wp = W2t + (nBase + nt * 16 + col) * NH + quad * 8;
        short8 bf0 = *(const short8*)(wp);
        short8 bf1 = *(const short8*)(wp + 32);
        acc[0][nt] = __builtin_amdgcn_mfma_f32_16x16x32_bf16(afrag[0][0], bf0, acc[0][nt], 0, 0, 0);
        acc[1][nt] = __builtin_amdgcn_mfma_f32_16x16x32_bf16(afrag[1][0], bf0, acc[1][nt], 0, 0, 0);
        acc[0][nt] = __builtin_amdgcn_mfma_f32_16x16x32_bf16(afrag[0][1], bf1, acc[0][nt], 0, 0, 0);
        acc[1][nt] = __builtin_amdgcn_mfma_f32_16x16x32_bf16(afrag[1][1], bf1, acc[1][nt], 0, 0, 0);
    }

#pragma unroll
    for (int nt = 0; nt < 8; ++nt) {
        float bias = b2[nBase + nt * 16 + col];
#pragma unroll
        for (int mt = 0; mt < 2; ++mt) {
            int mRow = tokBase + mt * 16 + quad * 4;
            size_t base = (size_t)mRow * ND + nBase + nt * 16 + col;
#pragma unroll
            for (int r = 0; r < 4; ++r) {
                out[base + (size_t)r * ND] = acc[mt][nt][r] + bias;
            }
        }
    }
}

extern "C" void kernel_launch(void* const* d_in, const int* in_sizes, int n_in,
                              void* d_out, int out_size, void* d_ws, size_t ws_size,
                              hipStream_t stream) {
    const float* tok  = (const float*)d_in[0];
    const int*   mask = (const int*)d_in[1];
    const float* W1   = (const float*)d_in[2];
    const float* b1   = (const float*)d_in[3];
    const float* W2   = (const float*)d_in[4];
    const float* b2   = (const float*)d_in[5];
    float*       out  = (float*)d_out;

    float4*         P       = (float4*)d_ws;                                   // 512 KB
    float*          massBuf = (float*)((char*)d_ws + (size_t)NB * NT * 16);    // 384 KB
    unsigned short* W2t     = (unsigned short*)((char*)d_ws + (size_t)NB * NT * 16
                                                + (size_t)NB * NT * 3 * 4);    // 64 KB

    compute_P_kernel<<<dim3(NB * NT / 256), dim3(256), 0, stream>>>(tok, mask, P, W2t, W2);

    dim3 gB(NT / 64, NB);
    topk_mass_kernel<<<gB, dim3(512), 0, stream>>>(P, mask, massBuf);

    mlp_kernel<<<dim3(NB * NT / 32), dim3(256), 0, stream>>>(massBuf, W1, b1, W2t, b2, out);
}

// Round 8
// 133.559 us; speedup vs baseline: 1.1746x; 1.1746x over previous
//
#include <hip/hip_runtime.h>
#include <hip/hip_bf16.h>
#include <math.h>

#define NB 16
#define NT 2048
#define ND 512
#define NH 64

typedef __attribute__((ext_vector_type(8))) short short8;
typedef __attribute__((ext_vector_type(4))) float float4v;

// ---------------------------------------------------------------------------
// mask dtype robustness: byte layout -> first int32 reads 0x01010101 (lengths
// >= T/2 so mask[0..3] all true); int32 layout -> 1; f32 layout -> 0x3F800000.
// ---------------------------------------------------------------------------
__device__ __forceinline__ bool mask_is_bytes(const int* m) {
    return m[0] == 0x01010101;
}
__device__ __forceinline__ bool mask_at(const int* m, bool bytes, int i) {
    if (bytes) return ((const unsigned char*)m)[i] != 0;
    return m[i] != 0;
}

// Minkowski dot, metric folded into `a`; explicit fmaf so pass 1 / pass 2
// recompute bitwise-identical values.
__device__ __forceinline__ float dot4(float4 a, float4 p) {
    float d = a.x * p.x;
    d = __builtin_fmaf(a.y, p.y, d);
    d = __builtin_fmaf(a.z, p.z, d);
    d = __builtin_fmaf(a.w, p.w, d);
    return d;
}

__device__ __forceinline__ unsigned short f2bf(float x) {
    unsigned int u = __float_as_uint(x);
    u += 0x7fffu + ((u >> 16) & 1u);
    return (unsigned short)(u >> 16);
}

// ---------------------------------------------------------------------------
// Kernel A: one-time W2 fp32[k][n] -> bf16 W2t[n][k]. 32768 threads.
// ---------------------------------------------------------------------------
__global__ void __launch_bounds__(256) w2t_kernel(
        const float* __restrict__ W2, unsigned short* __restrict__ W2t) {
    int i = blockIdx.x * 256 + threadIdx.x;
    int n = i & (ND - 1), k = i >> 9;
    W2t[n * NH + k] = f2bf(W2[k * ND + n]);
}

// ---------------------------------------------------------------------------
// Kernel B: fused (R5 design, bug-fixed: out row includes b*NT).
// 512 thr (8 waves), block owns 64 tokens.
//  1) stage P (computed in-flight from tokens) into LDS; L via ballot
//  2) per-wave top-8 over its L/8 chunk (med3 chain, exact fp32)
//  3) merge 64 candidates -> th2/th4/th8 (redundant per wave, in-register)
//  4) exact-membership partial sums -> per-wave psum (scratch reuses vtop)
//  5) wave 0: reduce + invariant masses -> mass_s
//  6) h = gelu(mass@W1+b1) bf16 -> LDS
//  7) MFMA 64x512 @ W2t + b2 -> out   (LDS ~67.8 KB -> 2 blocks/CU)
// ---------------------------------------------------------------------------
#define VT(w2, j, l)  scratch[((w2) * 8 + (j)) * 64 + (l)]
#define PS(w2, c, l)  scratch[((w2) * 12 + (c)) * 64 + (l)]

__global__ void __launch_bounds__(512) fused_topk_mass_mlp_kernel(
        const float* __restrict__ tok,
        const int* __restrict__ mask,
        const float* __restrict__ W1,
        const float* __restrict__ b1,
        const unsigned short* __restrict__ W2t,
        const float* __restrict__ b2,
        float* __restrict__ out) {
    __shared__ float Plds[NT * 4];            // 32 KB
    __shared__ float scratch[8 * 12 * 64];    // 24 KB (vtop, then psum)
    __shared__ unsigned short hs[64][88];     // 11 KB
    __shared__ float mass_s[3][64];           // 768 B
    __shared__ int wcnt[8];

    const int b    = blockIdx.y;
    const int t0   = blockIdx.x * 64;
    const int tid  = threadIdx.x;
    const int lane = tid & 63;
    const int w    = tid >> 6;
    const bool mb  = mask_is_bytes(mask);

    const bool blockValid = mask_at(mask, mb, b * NT + t0);

    if (blockValid) {
        // ---- stage tokens -> P in LDS; count L ----
        int cnt = 0;
#pragma unroll
        for (int it = 0; it < 4; ++it) {
            int i = tid + it * 512;
            float4 tv = ((const float4*)tok)[b * NT + i];
            bool m = mask_at(mask, mb, b * NT + i);
            float E = tv.x, Pt = tv.y, eta = tv.z, phi = tv.w;
            float px = Pt * cosf(phi);
            float py = Pt * sinf(phi);
            float pz = Pt * sinhf(fminf(fmaxf(eta, -20.f), 20.f));
            float4 pv = m ? make_float4(E, px, py, pz)
                          : make_float4(-1e30f, 0.f, 0.f, 0.f);
            *(float4*)&Plds[i * 4] = pv;
            cnt += (int)__popcll(__ballot(m));
        }
        if (lane == 0) wcnt[w] = cnt;
        __syncthreads();                               // B1

        int L = 0;
#pragma unroll
        for (int j = 0; j < 8; ++j) L += wcnt[j];
        const int C    = (L + 7) >> 3;
        const int sBeg = w * C;
        const int sEnd = min(sBeg + C, L);

        float4 pt = *(const float4*)&Plds[(t0 + lane) * 4];
        float4 a  = make_float4(pt.x, -pt.y, -pt.z, -pt.w);

        const float NEGBIG = -3.402823466e38f;
        float v0 = NEGBIG, v1 = NEGBIG, v2 = NEGBIG, v3 = NEGBIG;
        float v4 = NEGBIG, v5 = NEGBIG, v6 = NEGBIG, v7 = NEGBIG;

        // ---- pass 1: chunk-local top-8 ----
#pragma unroll 4
        for (int s = sBeg; s < sEnd; ++s) {
            float4 ps = *(const float4*)&Plds[s * 4];
            float d = dot4(a, ps);
            float n0 = fmaxf(v0, d);
            float n1 = __builtin_amdgcn_fmed3f(d, v0, v1);
            float n2 = __builtin_amdgcn_fmed3f(d, v1, v2);
            float n3 = __builtin_amdgcn_fmed3f(d, v2, v3);
            float n4 = __builtin_amdgcn_fmed3f(d, v3, v4);
            float n5 = __builtin_amdgcn_fmed3f(d, v4, v5);
            float n6 = __builtin_amdgcn_fmed3f(d, v5, v6);
            float n7 = __builtin_amdgcn_fmed3f(d, v6, v7);
            v0 = n0; v1 = n1; v2 = n2; v3 = n3;
            v4 = n4; v5 = n5; v6 = n6; v7 = n7;
        }
        VT(w, 0, lane) = v0; VT(w, 1, lane) = v1;
        VT(w, 2, lane) = v2; VT(w, 3, lane) = v3;
        VT(w, 4, lane) = v4; VT(w, 5, lane) = v5;
        VT(w, 6, lane) = v6; VT(w, 7, lane) = v7;
        __syncthreads();                               // B2

        // ---- merge 64 candidates (redundant per wave) ----
        float m0 = NEGBIG, m1 = NEGBIG, m2_ = NEGBIG, m3 = NEGBIG;
        float m4 = NEGBIG, m5 = NEGBIG, m6 = NEGBIG, m7 = NEGBIG;
#pragma unroll
        for (int w2 = 0; w2 < 8; ++w2) {
#pragma unroll
            for (int j = 0; j < 8; ++j) {
                float d = VT(w2, j, lane);
                float n0 = fmaxf(m0, d);
                float n1 = __builtin_amdgcn_fmed3f(d, m0, m1);
                float n2 = __builtin_amdgcn_fmed3f(d, m1, m2_);
                float n3 = __builtin_amdgcn_fmed3f(d, m2_, m3);
                float n4 = __builtin_amdgcn_fmed3f(d, m3, m4);
                float n5 = __builtin_amdgcn_fmed3f(d, m4, m5);
                float n6 = __builtin_amdgcn_fmed3f(d, m5, m6);
                float n7 = __builtin_amdgcn_fmed3f(d, m6, m7);
                m0 = n0; m1 = n1; m2_ = n2; m3 = n3;
                m4 = n4; m5 = n5; m6 = n6; m7 = n7;
            }
        }
        const float th2 = m1, th4 = m3, th8 = m7;
        __syncthreads();                               // B3 (vtop dead)

        // ---- pass 2: exact-membership partial sums ----
        float s2x = 0.f, s2y = 0.f, s2z = 0.f, s2w = 0.f;
        float s4x = 0.f, s4y = 0.f, s4z = 0.f, s4w = 0.f;
        float s8x = 0.f, s8y = 0.f, s8z = 0.f, s8w = 0.f;
#pragma unroll 4
        for (int s = sBeg; s < sEnd; ++s) {
            float4 ps = *(const float4*)&Plds[s * 4];
            float d = dot4(a, ps);
            if (d >= th8) {
                s8x += ps.x; s8y += ps.y; s8z += ps.z; s8w += ps.w;
                if (d >= th4) {
                    s4x += ps.x; s4y += ps.y; s4z += ps.z; s4w += ps.w;
                    if (d >= th2) {
                        s2x += ps.x; s2y += ps.y; s2z += ps.z; s2w += ps.w;
                    }
                }
            }
        }
        PS(w, 0, lane) = s2x;  PS(w, 1, lane) = s2y;
        PS(w, 2, lane) = s2z;  PS(w, 3, lane) = s2w;
        PS(w, 4, lane) = s4x;  PS(w, 5, lane) = s4y;
        PS(w, 6, lane) = s4z;  PS(w, 7, lane) = s4w;
        PS(w, 8, lane) = s8x;  PS(w, 9, lane) = s8y;
        PS(w, 10, lane) = s8z; PS(w, 11, lane) = s8w;
        __syncthreads();                               // B4

        // ---- wave 0: reduce + masses ----
        if (w == 0) {
            float tot[12];
#pragma unroll
            for (int c = 0; c < 12; ++c) {
                float acc = 0.f;
#pragma unroll
                for (int w2 = 0; w2 < 8; ++w2) acc += PS(w2, c, lane);
                tot[c] = acc;
            }
            const bool maskt = (t0 + lane) < L;   // mask monotone
            const float MZ = sqrtf(1e-8f);
            auto massf = [&](float sx, float sy, float sz, float sw) -> float {
                float q = sx * sx;
                q = __builtin_fmaf(-sy, sy, q);
                q = __builtin_fmaf(-sz, sz, q);
                q = __builtin_fmaf(-sw, sw, q);
                q = fmaxf(q, 0.f);
                return sqrtf(q + 1e-8f);
            };
            mass_s[0][lane] = maskt ? massf(tot[0], tot[1], tot[2], tot[3]) : MZ;
            mass_s[1][lane] = maskt ? massf(tot[4], tot[5], tot[6], tot[7]) : MZ;
            mass_s[2][lane] = maskt ? massf(tot[8], tot[9], tot[10], tot[11]) : MZ;
        }
    } else {
        if (tid < 64) {
            const float MZ = sqrtf(1e-8f);
            mass_s[0][tid] = MZ;
            mass_s[1][tid] = MZ;
            mass_s[2][tid] = MZ;
        }
    }
    __syncthreads();                                   // B5 (common)

    // ---- h = gelu(mass @ W1 + b1), bf16 -> LDS ----
    {
        const int tt = lane;
        const int hr = w;                  // wave-uniform -> W1/b1 scalar loads
        float q0 = mass_s[0][tt];
        float q1 = mass_s[1][tt];
        float q2 = mass_s[2][tt];
        unsigned short hv[8];
#pragma unroll
        for (int j = 0; j < 8; ++j) {
            int hh = hr * 8 + j;
            float pre = b1[hh];
            pre = __builtin_fmaf(q0, W1[hh], pre);
            pre = __builtin_fmaf(q1, W1[NH + hh], pre);
            pre = __builtin_fmaf(q2, W1[2 * NH + hh], pre);
            float g = 0.5f * pre * (1.0f + erff(pre * 0.70710678118654752f));
            hv[j] = f2bf(g);
        }
        *(short8*)&hs[tt][hr * 8] = *(const short8*)hv;
    }
    __syncthreads();                                   // B6

    // ---- MFMA: out[b*NT + t0 .. +63][0..511] = h @ W2 + b2 ----
    const int col   = lane & 15;
    const int quad  = lane >> 4;
    const int mhalf = w >> 2;              // token half (0..1)
    const int nBase = (w & 3) * 128;

    short8 afrag[2][2];
#pragma unroll
    for (int mt = 0; mt < 2; ++mt)
#pragma unroll
        for (int ks = 0; ks < 2; ++ks)
            afrag[mt][ks] = *(const short8*)&hs[mhalf * 32 + mt * 16 + col][ks * 32 + quad * 8];

    float4v acc[2][8];
#pragma unroll
    for (int mt = 0; mt < 2; ++mt)
#pragma unroll
        for (int nt = 0; nt < 8; ++nt)
            acc[mt][nt] = (float4v)(0.f);

#pragma unroll
    for (int nt = 0; nt < 8; ++nt) {
        const unsigned short* wp = W2t + (nBase + nt * 16 + col) * NH + quad * 8;
        short8 bf0 = *(const short8*)(wp);
        short8 bf1 = *(const short8*)(wp + 32);
        acc[0][nt] = __builtin_amdgcn_mfma_f32_16x16x32_bf16(afrag[0][0], bf0, acc[0][nt], 0, 0, 0);
        acc[1][nt] = __builtin_amdgcn_mfma_f32_16x16x32_bf16(afrag[1][0], bf0, acc[1][nt], 0, 0, 0);
        acc[0][nt] = __builtin_amdgcn_mfma_f32_16x16x32_bf16(afrag[0][1], bf1, acc[0][nt], 0, 0, 0);
        acc[1][nt] = __builtin_amdgcn_mfma_f32_16x16x32_bf16(afrag[1][1], bf1, acc[1][nt], 0, 0, 0);
    }

#pragma unroll
    for (int nt = 0; nt < 8; ++nt) {
        float bias = b2[nBase + nt * 16 + col];
#pragma unroll
        for (int mt = 0; mt < 2; ++mt) {
            // THE R5 BUG FIX: row index includes b*NT.
            int mRow = b * NT + t0 + mhalf * 32 + mt * 16 + quad * 4;
            size_t base = (size_t)mRow * ND + nBase + nt * 16 + col;
#pragma unroll
            for (int r = 0; r < 4; ++r) {
                out[base + (size_t)r * ND] = acc[mt][nt][r] + bias;
            }
        }
    }
}

extern "C" void kernel_launch(void* const* d_in, const int* in_sizes, int n_in,
                              void* d_out, int out_size, void* d_ws, size_t ws_size,
                              hipStream_t stream) {
    const float* tok  = (const float*)d_in[0];
    const int*   mask = (const int*)d_in[1];   // layout auto-detected in-kernel
    const float* W1   = (const float*)d_in[2];
    const float* b1   = (const float*)d_in[3];
    const float* W2   = (const float*)d_in[4];
    const float* b2   = (const float*)d_in[5];
    float*       out  = (float*)d_out;

    unsigned short* W2t = (unsigned short*)d_ws;       // 64 KB

    w2t_kernel<<<dim3(ND * NH / 256), dim3(256), 0, stream>>>(W2, W2t);

    dim3 gB(NT / 64, NB);
    fused_topk_mass_mlp_kernel<<<gB, dim3(512), 0, stream>>>(
        tok, mask, W1, b1, W2t, b2, out);
}